// Round 3
// baseline (211.230 us; speedup 1.0000x reference)
//
#include <hip/hip_runtime.h>
#include <hip/hip_bf16.h>

#define DIM    768
#define HEADS  12
#define DHEAD  64
#define BATCH  4
#define SEQ    2048
#define NROW   (BATCH * SEQ)   // 8192
#define QKVN   (3 * DIM)       // 2304
#define FACTOR 0.125f          // 64^-0.5
#define QSCALE 0.18033688011112042f  // FACTOR * log2(e), folded into Wqt rows <768

typedef __attribute__((ext_vector_type(8))) short short8;   // 8 bf16 = 4 VGPR
typedef __attribute__((ext_vector_type(4))) float floatx4;  // 16x16 C/D
typedef __attribute__((ext_vector_type(4))) unsigned uintx4;

__device__ __forceinline__ floatx4 mfma16(short8 a, short8 b, floatx4 c) {
    return __builtin_amdgcn_mfma_f32_16x16x32_bf16(a, b, c, 0, 0, 0);
}

// async global->LDS, 16B per lane; lds base must be wave-uniform,
// deposits at base + lane*16 (lane-ordered source REQUIRED for coalescing)
__device__ __forceinline__ void glds16(const void* g, void* l) {
    __builtin_amdgcn_global_load_lds((const __attribute__((address_space(1))) void*)g,
                                     (__attribute__((address_space(3))) void*)l,
                                     16, 0, 0);
}

// branchless RNE fp32->bf16 (finite values only)
__device__ __forceinline__ short rne16(float f) {
    unsigned u = __builtin_bit_cast(unsigned, f);
    return (short)((u + 0x7fffu + ((u >> 16) & 1u)) >> 16);
}
__device__ __forceinline__ unsigned pack2(float lo, float hi) {
    unsigned ul = __builtin_bit_cast(unsigned, lo);
    unsigned uh = __builtin_bit_cast(unsigned, hi);
    ul = (ul + 0x7fffu + ((ul >> 16) & 1u)) >> 16;
    uh = (uh + 0x7fffu + ((uh >> 16) & 1u)) & 0xffff0000u;
    return ul | uh;
}
// HW packed RNE cvt (gfx950): lo -> bits[15:0], hi -> bits[31:16]
__device__ __forceinline__ unsigned cvtpk(float lo, float hi) {
    unsigned r;
    asm("v_cvt_pk_bf16_f32 %0, %1, %2" : "=v"(r) : "v"(lo), "v"(hi));
    return r;
}

// XOR-swizzled tile addressing: 64 bf16 per row, swizzle 16B chunks.
__device__ __forceinline__ int swz8(int row, int col) {
    return (row << 6) + ((((col >> 3) ^ row) & 7) << 3) + (col & 7);
}

// ---------------------------------------------------------------------------
// prep (fused): blocks [0,6144)   : x fp32 -> bf16
//               blocks [6144,7872): Wqkv transpose+permute (+QSCALE rows<768)
//               blocks [7872,8448): Wout transpose
// ---------------------------------------------------------------------------
__global__ __launch_bounds__(256) void prep(const float* __restrict__ x,
                                            short* __restrict__ xb,
                                            const float* __restrict__ Wqkv,
                                            short* __restrict__ Wqt,
                                            const float* __restrict__ Wout,
                                            short* __restrict__ Wot) {
    __shared__ short T[32][33];
    int blk = blockIdx.x;
    if (blk < 6144) {
        int g = blk * 256 + threadIdx.x;
        float4 v = ((const float4*)x)[g];
        uint2 o;
        o.x = pack2(v.x, v.y);
        o.y = pack2(v.z, v.w);
        ((uint2*)xb)[g] = o;
        return;
    }
    blk -= 6144;
    const float* W;
    short* Wt;
    int N, permute, bx, by;
    if (blk < 1728) { W = Wqkv; Wt = Wqt; N = QKVN; permute = 1; bx = blk % 72; by = blk / 72; }
    else { blk -= 1728; W = Wout; Wt = Wot; N = DIM; permute = 0; bx = blk % 24; by = blk / 24; }

    int n0 = bx * 32, k0 = by * 32;
    int c = threadIdx.x & 31, r0 = threadIdx.x >> 5;
    for (int r = r0; r < 32; r += 8)
        T[r][c] = rne16(W[(size_t)(k0 + r) * N + n0 + c]);
    __syncthreads();
    for (int r = r0; r < 32; r += 8) {
        int n = n0 + r;
        int np = n;
        float scale = 1.0f;
        if (permute) {
            int d = n / 36, rem = n - d * 36;
            int which = rem / 12, h = rem - which * 12;
            np = which * 768 + h * 64 + d;
            if (which == 0) scale = QSCALE;
        }
        float v = __bfloat162float(__hip_bfloat16_raw{(unsigned short)T[c][r]});
        Wt[(size_t)np * DIM + k0 + c] = (scale == 1.0f) ? T[c][r] : rne16(v * scale);
    }
}

// ---------------------------------------------------------------------------
// qkv = xb @ Wqkv (via permuted Wqt [2304][768]); glds-staged.
// Outputs Q,K,V^T as XOR-swizzled 64x64 tiles [bh][32 tiles][4096 shorts].
// Q/K waves run the MFMA with SWAPPED operands (C^T): lane holds 4
// consecutive d at fixed t -> packed uint2 stores (16/lane, not 64 scalar).
// V waves keep orientation (4 consecutive t at fixed d) -> LDS transpose.
// ---------------------------------------------------------------------------
__global__ __launch_bounds__(256) void gemm_qkv(const short* __restrict__ A,
                                                const short* __restrict__ Bt,
                                                short* __restrict__ Qo,
                                                short* __restrict__ Ko,
                                                short* __restrict__ Vto) {
    __shared__ short As[128 * 64];
    __shared__ short Bs[128 * 64];
    const int tid = threadIdx.x;
    const int lane = tid & 63, wave = tid >> 6;
    const int l15 = lane & 15, quad = lane >> 4;

    // XCD swizzle: 8 XCDs x 8 m x 18 n = 1152 blocks
    const int flat = blockIdx.x;
    const int xcd = flat & 7;
    const int local = flat >> 3;
    const int mloc = local & 7, nloc = local >> 3;
    const int m0 = (xcd * 8 + mloc) * 128;
    const int n0 = nloc * 128;

    const int wm = (wave >> 1) * 64, wn = (wave & 1) * 64;
    const int r8 = wave * 8 + (lane >> 3);
    const int c8 = lane & 7;
    const int sc = ((c8 ^ (r8 & 7)) << 3);   // swizzled source chunk (elems)

    const int sn = n0 + wn;                  // wave-uniform output chunk
    const int which = sn / 768;
    const bool swapAB = (which != 2);        // Q/K waves compute C^T

    floatx4 acc[4][4] = {};
    for (int k0 = 0; k0 < DIM; k0 += 64) {
#pragma unroll
        for (int i = 0; i < 4; ++i) {
            int row = i * 32 + r8;
            glds16(&A[(size_t)(m0 + row) * DIM + k0 + sc], &As[(size_t)(i * 32 + wave * 8) * 64]);
            glds16(&Bt[(size_t)(n0 + row) * DIM + k0 + sc], &Bs[(size_t)(i * 32 + wave * 8) * 64]);
        }
        __syncthreads();
#pragma unroll
        for (int ks = 0; ks < 2; ++ks) {
            short8 a[4], b[4];
#pragma unroll
            for (int mt = 0; mt < 4; ++mt)
                a[mt] = *(const short8*)&As[swz8(wm + mt * 16 + l15, ks * 32 + quad * 8)];
#pragma unroll
            for (int nt = 0; nt < 4; ++nt)
                b[nt] = *(const short8*)&Bs[swz8(wn + nt * 16 + l15, ks * 32 + quad * 8)];
            if (swapAB) {
#pragma unroll
                for (int mt = 0; mt < 4; ++mt)
#pragma unroll
                    for (int nt = 0; nt < 4; ++nt)
                        acc[mt][nt] = mfma16(b[nt], a[mt], acc[mt][nt]);
            } else {
#pragma unroll
                for (int mt = 0; mt < 4; ++mt)
#pragma unroll
                    for (int nt = 0; nt < 4; ++nt)
                        acc[mt][nt] = mfma16(a[mt], b[nt], acc[mt][nt]);
            }
        }
        __syncthreads();
    }

    // ---- epilogue ----
    const int h = (sn - which * 768) >> 6;
    const int bb = (m0 + wm) >> 11;
    const int tbase = (m0 + wm) & 2047;
    const size_t tilebase = ((size_t)(bb * HEADS + h) * 32 + (tbase >> 6)) * 4096;

    if (which != 2) {
        // swapped acc: lane covers t = mt*16+l15, d = nt*16+quad*4..+3
        short* dst = (which == 0) ? Qo : Ko;
#pragma unroll
        for (int mt = 0; mt < 4; ++mt)
#pragma unroll
            for (int nt = 0; nt < 4; ++nt) {
                int tl = mt * 16 + l15;
                int d0 = nt * 16 + quad * 4;
                uint2 pk;
                pk.x = pack2(acc[mt][nt][0], acc[mt][nt][1]);
                pk.y = pack2(acc[mt][nt][2], acc[mt][nt][3]);
                *(uint2*)&dst[tilebase + swz8(tl, d0)] = pk;
            }
    } else {
        // V: build the swizzled V^T 64x64 tile in LDS (vld IS the tile image)
        short* vld = ((wave < 2) ? As : Bs) + (wave & 1) * 4096;  // 64x64
#pragma unroll
        for (int mt = 0; mt < 4; ++mt)
#pragma unroll
            for (int nt = 0; nt < 4; ++nt) {
                int d = nt * 16 + l15;
                int tl = mt * 16 + quad * 4;
                int chunk = (tl >> 3) ^ (d & 7);
                int addr = (d << 6) + (chunk << 3) + (tl & 7);   // = swz8(d, tl)
                uint2 pk;
                pk.x = pack2(acc[mt][nt][0], acc[mt][nt][1]);
                pk.y = pack2(acc[mt][nt][2], acc[mt][nt][3]);
                *(uint2*)&vld[addr] = pk;
            }
    }
    __syncthreads();
    if (which == 2) {
        // linear dump of the swizzled tile -> perfectly coalesced dwordx4
        short* vld = ((wave < 2) ? As : Bs) + (wave & 1) * 4096;
#pragma unroll
        for (int i = 0; i < 8; ++i) {
            int c = (i * 64 + lane) * 8;
            *(uint4*)&Vto[tilebase + c] = *(const uint4*)&vld[c];
        }
    }
}

// ---------------------------------------------------------------------------
// MFMA flash attention, 8 waves x 16 q-rows, P fully IN-REGISTER:
//   - QK^T (swapped) leaves P fragments in regs; redistribution to the PV
//     B-fragment layout is 8 permlane ops (permlane32_swap + permlane16_swap
//     per dword pair) -- NO LDS round trip, no lgkm waits, no P strips.
//   - K/V double-buffered in LDS (32 KB total), prefetch after the single
//     per-iter barrier (T3 minimum-2-phase).
//   - per-lane epilogue normalization (inv at l15 = q), packed stores.
// Mapping (verified both directions):
//   have:  lane(quad,l15) D[kt][j] = P[q=l15][kv=kt*16+quad*4+2j..+1]
//   need:  pf[ks] dword m = P[q=l15][kv=ks*32+quad*8+2m..+1]
//   for X=D[2ks][j], Y=D[2ks+1][j]:
//     P32(X,Y):  X'=[X@0,X@1,Y@0,Y@1]  Y'=[X@2,X@3,Y@2,Y@3]   (by quad)
//     P16(X',Y'): X''=[X@0,X@2,Y@0,Y@2]=m(j)  Y''=[X@1,X@3,Y@1,Y@3]=m(j+2)
// ---------------------------------------------------------------------------
__global__ __launch_bounds__(512, 6) void attn_mfma(const short* __restrict__ Q,
                                                    const short* __restrict__ K,
                                                    const short* __restrict__ Vt,
                                                    short* __restrict__ O) {
    // [0,16384): K/V double buffer (2 x (K 4096 | V 4096) shorts) = 32 KB
    __shared__ __align__(16) short smem[16384];
    const int tid = threadIdx.x;
    const int lane = tid & 63, wave = tid >> 6;
    const int l15 = lane & 15, quad = lane >> 4;
    const int flat = blockIdx.x;
    const int xcd = flat & 7, li = flat >> 3;      // li 0..95
    const int bh = xcd + (li % 6) * 8;             // bh % 8 == xcd (K/V L2-local)
    const int q0 = (li / 6) * 128;
    const size_t base = (size_t)bh * SEQ * DHEAD;  // shorts; = bh*32 tiles
    const int lane8 = lane * 8;

    // ---- stage Q (2 swizzled tiles, 16 KB) into smem[0..8191] ----
    {
        size_t qtb = base + (size_t)(q0 >> 6) * 4096;
#pragma unroll
        for (int c = 0; c < 2; ++c) {
            int i = wave * 2 + c;
            glds16(&Q[qtb + (size_t)i * 512 + lane8], &smem[i * 512]);
        }
    }
    __syncthreads();
    short8 qf[2];   // wave's 16 q rows: [ks]
#pragma unroll
    for (int ks = 0; ks < 2; ++ks)
        qf[ks] = *(const short8*)&smem[(wave >> 2) * 4096 +
                                       swz8((wave & 3) * 16 + l15,
                                            ks * 32 + quad * 8)];
    __syncthreads();   // Q in regs; smem free for K/V dbuf

    floatx4 o[4] = {};           // [dt]: C col=q(l15), row=d(quad*4+r)
    float lsum = 0.f;

    // prologue: stage kv-tile 0 into buf0 (1 K chunk + 1 V chunk per wave)
    glds16(&K[base + wave * 512 + lane8], &smem[wave * 512]);
    glds16(&Vt[base + wave * 512 + lane8], &smem[4096 + wave * 512]);

    for (int t = 0; t < 32; ++t) {
        __syncthreads();          // implicit vmcnt(0): tile t resident; other buf free
        short* Ks = smem + (t & 1) * 8192;
        short* Vs = Ks + 4096;
        if (t < 31) {             // prefetch t+1; drains only at NEXT barrier
            size_t ktb = base + (size_t)(t + 1) * 4096;
            short* nb = smem + ((t + 1) & 1) * 8192;
            glds16(&K[ktb + wave * 512 + lane8], &nb[wave * 512]);
            glds16(&Vt[ktb + wave * 512 + lane8], &nb[4096 + wave * 512]);
        }

        // ---- S^T = K . Q^T : sa[kt], kv = kt*16+quad*4+r, q = l15 ----
        floatx4 sa[4] = {};
        __builtin_amdgcn_s_setprio(1);
#pragma unroll
        for (int ks = 0; ks < 2; ++ks)
#pragma unroll
            for (int kt = 0; kt < 4; ++kt) {
                short8 kf = *(const short8*)&Ks[swz8(kt * 16 + l15, ks * 32 + quad * 8)];
                sa[kt] = mfma16(kf, qf[ks], sa[kt]);
            }
        __builtin_amdgcn_s_setprio(0);

        // ---- p = exp2(s), pack to bf16 pairs (all register-resident) ----
        unsigned D0[2], D1[2], D2[2], D3[2];   // D[kt][j]
        {
            float p0, p1, p2, p3;
#define SM_KT(kt, Dk)                                              \
            p0 = __builtin_amdgcn_exp2f(sa[kt][0]);                \
            p1 = __builtin_amdgcn_exp2f(sa[kt][1]);                \
            p2 = __builtin_amdgcn_exp2f(sa[kt][2]);                \
            p3 = __builtin_amdgcn_exp2f(sa[kt][3]);                \
            lsum += (p0 + p1) + (p2 + p3);                         \
            Dk[0] = cvtpk(p0, p1);                                 \
            Dk[1] = cvtpk(p2, p3);
            SM_KT(0, D0) SM_KT(1, D1) SM_KT(2, D2) SM_KT(3, D3)
#undef SM_KT
        }

        // ---- in-register redistribution: D[kt][j] -> pf[ks] (8 permlanes) ----
        short8 pf[2];
        {
            unsigned a0 = D0[0], b0 = D1[0], a1 = D0[1], b1 = D1[1];
            asm("v_permlane32_swap_b32 %0, %1" : "+v"(a0), "+v"(b0));
            asm("v_permlane16_swap_b32 %0, %1" : "+v"(a0), "+v"(b0));
            asm("v_permlane32_swap_b32 %0, %1" : "+v"(a1), "+v"(b1));
            asm("v_permlane16_swap_b32 %0, %1" : "+v"(a1), "+v"(b1));
            uintx4 w0 = {a0, a1, b0, b1};      // m0,m1,m2,m3
            pf[0] = __builtin_bit_cast(short8, w0);
            unsigned c0 = D2[0], d0 = D3[0], c1 = D2[1], d1 = D3[1];
            asm("v_permlane32_swap_b32 %0, %1" : "+v"(c0), "+v"(d0));
            asm("v_permlane16_swap_b32 %0, %1" : "+v"(c0), "+v"(d0));
            asm("v_permlane32_swap_b32 %0, %1" : "+v"(c1), "+v"(d1));
            asm("v_permlane16_swap_b32 %0, %1" : "+v"(c1), "+v"(d1));
            uintx4 w1 = {c0, c1, d0, d1};
            pf[1] = __builtin_bit_cast(short8, w1);
        }

        // ---- O^T += V^T . P^T (A=V^T rows d, B=pf cols q) ----
        __builtin_amdgcn_s_setprio(1);
#pragma unroll
        for (int ks = 0; ks < 2; ++ks)
#pragma unroll
            for (int dt = 0; dt < 4; ++dt) {
                short8 vf = *(const short8*)&Vs[swz8(dt * 16 + l15, ks * 32 + quad * 8)];
                o[dt] = mfma16(vf, pf[ks], o[dt]);
            }
        __builtin_amdgcn_s_setprio(0);
    }

    // ---- epilogue: per-lane normalization (q = l15), packed stores ----
    float s = lsum;
    s += __shfl_xor(s, 16);
    s += __shfl_xor(s, 32);
    float inv = 1.f / s;

    const int b = bh / HEADS, h = bh - b * HEADS;
    const int tq = q0 + wave * 16 + l15;
    size_t rowo = ((size_t)(b * SEQ + tq)) * DIM + h * DHEAD + quad * 4;
#pragma unroll
    for (int dt = 0; dt < 4; ++dt) {
        uint2 pk;
        pk.x = cvtpk(o[dt][0] * inv, o[dt][1] * inv);
        pk.y = cvtpk(o[dt][2] * inv, o[dt][3] * inv);
        *(uint2*)&O[rowo + dt * 16] = pk;
    }
}

// ---------------------------------------------------------------------------
// out = attnB @ Wout (via Wot [768][768]), fp32 output; glds-staged.
// All waves SWAP operands (C^T): lane holds 4 consecutive n at fixed m ->
// one dwordx4 store per acc (16/lane, not 64 scalar dwords).
// ---------------------------------------------------------------------------
__global__ __launch_bounds__(256) void gemm_out(const short* __restrict__ A,
                                                const short* __restrict__ Bt,
                                                float* __restrict__ out) {
    __shared__ short As[128 * 64];
    __shared__ short Bs[128 * 64];
    const int tid = threadIdx.x;
    const int lane = tid & 63, wave = tid >> 6;
    const int l15 = lane & 15, quad = lane >> 4;
    const int m0 = blockIdx.y * 128, n0 = blockIdx.x * 128;
    const int wm = (wave >> 1) * 64, wn = (wave & 1) * 64;
    const int r8 = wave * 8 + (lane >> 3);
    const int sc = (((lane & 7) ^ (r8 & 7)) << 3);

    floatx4 acc[4][4] = {};
    for (int k0 = 0; k0 < DIM; k0 += 64) {
#pragma unroll
        for (int i = 0; i < 4; ++i) {
            int row = i * 32 + r8;
            glds16(&A[(size_t)(m0 + row) * DIM + k0 + sc], &As[(size_t)(i * 32 + wave * 8) * 64]);
            glds16(&Bt[(size_t)(n0 + row) * DIM + k0 + sc], &Bs[(size_t)(i * 32 + wave * 8) * 64]);
        }
        __syncthreads();
#pragma unroll
        for (int ks = 0; ks < 2; ++ks) {
            short8 a[4], b[4];
#pragma unroll
            for (int mt = 0; mt < 4; ++mt)
                a[mt] = *(const short8*)&As[swz8(wm + mt * 16 + l15, ks * 32 + quad * 8)];
#pragma unroll
            for (int nt = 0; nt < 4; ++nt)
                b[nt] = *(const short8*)&Bs[swz8(wn + nt * 16 + l15, ks * 32 + quad * 8)];
#pragma unroll
            for (int mt = 0; mt < 4; ++mt)
#pragma unroll
                for (int nt = 0; nt < 4; ++nt)
                    acc[mt][nt] = mfma16(b[nt], a[mt], acc[mt][nt]);  // C^T
        }
        __syncthreads();
    }

    // swapped: m = wm+mt*16+l15, n = wn+nt*16+quad*4..+3 -> dwordx4 stores
#pragma unroll
    for (int mt = 0; mt < 4; ++mt)
#pragma unroll
        for (int nt = 0; nt < 4; ++nt) {
            int m = m0 + wm + mt * 16 + l15;
            int n = n0 + wn + nt * 16 + quad * 4;
            *(floatx4*)&out[(size_t)m * DIM + n] = acc[mt][nt];
        }
}

// ---------------------------------------------------------------------------
extern "C" void kernel_launch(void* const* d_in, const int* in_sizes, int n_in,
                              void* d_out, int out_size, void* d_ws, size_t ws_size,
                              hipStream_t stream) {
    const float* x    = (const float*)d_in[0];  // [4,2048,768] fp32
    const float* Wqkv = (const float*)d_in[1];  // [768,2304]  fp32
    const float* Wout = (const float*)d_in[2];  // [768,768]   fp32
    float* out = (float*)d_out;                 // [4,2048,768] fp32

    const size_t NE = (size_t)NROW * DIM;       // 6291456
    short* xb  = (short*)d_ws;                  // x bf16; later reused as attnB
    short* Wqt = xb + NE;                       // [2304][768] (col-permuted, Q-rows pre-scaled)
    short* Wot = Wqt + (size_t)QKVN * DIM;      // [768][768]
    short* Qw  = Wot + (size_t)DIM * DIM;       // swizzled tiles
    short* Kw  = Qw + NE;                       // swizzled tiles
    short* Vtw = Kw + NE;                       // swizzled V^T tiles

    prep<<<6144 + 1728 + 576, 256, 0, stream>>>(x, xb, Wqkv, Wqt, Wout, Wot);
    gemm_qkv<<<8 * 8 * 18, 256, 0, stream>>>(xb, Wqt, Qw, Kw, Vtw);
    // xb (x in bf16) is dead after gemm_qkv -> reuse as attention output buffer
    attn_mfma<<<768, 512, 0, stream>>>(Qw, Kw, Vtw, xb);
    gemm_out<<<dim3(DIM / 128, NROW / 128), 256, 0, stream>>>(xb, Wot, out);
}

// Round 4
// 210.089 us; speedup vs baseline: 1.0054x; 1.0054x over previous
//
#include <hip/hip_runtime.h>
#include <hip/hip_bf16.h>

#define DIM    768
#define HEADS  12
#define DHEAD  64
#define BATCH  4
#define SEQ    2048
#define NROW   (BATCH * SEQ)   // 8192
#define QKVN   (3 * DIM)       // 2304
#define FACTOR 0.125f          // 64^-0.5
#define QSCALE 0.18033688011112042f  // FACTOR * log2(e), folded into Wqt rows <768

typedef __attribute__((ext_vector_type(8))) short short8;    // 8 bf16 = 4 VGPR
typedef __attribute__((ext_vector_type(4))) float floatx4;   // 16x16 C/D
typedef __attribute__((ext_vector_type(16))) float floatx16; // 32x32 C/D
typedef __attribute__((ext_vector_type(4))) unsigned uintx4;

__device__ __forceinline__ floatx4 mfma16(short8 a, short8 b, floatx4 c) {
    return __builtin_amdgcn_mfma_f32_16x16x32_bf16(a, b, c, 0, 0, 0);
}
__device__ __forceinline__ floatx16 mfma32(short8 a, short8 b, floatx16 c) {
    return __builtin_amdgcn_mfma_f32_32x32x16_bf16(a, b, c, 0, 0, 0);
}

// async global->LDS, 16B per lane; lds base must be wave-uniform,
// deposits at base + lane*16 (lane-ordered source REQUIRED for coalescing)
__device__ __forceinline__ void glds16(const void* g, void* l) {
    __builtin_amdgcn_global_load_lds((const __attribute__((address_space(1))) void*)g,
                                     (__attribute__((address_space(3))) void*)l,
                                     16, 0, 0);
}

// branchless RNE fp32->bf16 (finite values only)
__device__ __forceinline__ short rne16(float f) {
    unsigned u = __builtin_bit_cast(unsigned, f);
    return (short)((u + 0x7fffu + ((u >> 16) & 1u)) >> 16);
}
__device__ __forceinline__ unsigned pack2(float lo, float hi) {
    unsigned ul = __builtin_bit_cast(unsigned, lo);
    unsigned uh = __builtin_bit_cast(unsigned, hi);
    ul = (ul + 0x7fffu + ((ul >> 16) & 1u)) >> 16;
    uh = (uh + 0x7fffu + ((uh >> 16) & 1u)) & 0xffff0000u;
    return ul | uh;
}
// HW packed RNE cvt (gfx950): lo -> bits[15:0], hi -> bits[31:16]
__device__ __forceinline__ unsigned cvtpk(float lo, float hi) {
    unsigned r;
    asm("v_cvt_pk_bf16_f32 %0, %1, %2" : "=v"(r) : "v"(lo), "v"(hi));
    return r;
}

// XOR-swizzled tile addressing (still used by the GEMM LDS staging paths)
__device__ __forceinline__ int swz8(int row, int col) {
    return (row << 6) + ((((col >> 3) ^ row) & 7) << 3) + (col & 7);
}

// ---------------------------------------------------------------------------
// prep (fused): blocks [0,6144)   : x fp32 -> bf16
//               blocks [6144,7872): Wqkv transpose+permute (+QSCALE rows<768)
//               blocks [7872,8448): Wout transpose
// ---------------------------------------------------------------------------
__global__ __launch_bounds__(256) void prep(const float* __restrict__ x,
                                            short* __restrict__ xb,
                                            const float* __restrict__ Wqkv,
                                            short* __restrict__ Wqt,
                                            const float* __restrict__ Wout,
                                            short* __restrict__ Wot) {
    __shared__ short T[32][33];
    int blk = blockIdx.x;
    if (blk < 6144) {
        int g = blk * 256 + threadIdx.x;
        float4 v = ((const float4*)x)[g];
        uint2 o;
        o.x = pack2(v.x, v.y);
        o.y = pack2(v.z, v.w);
        ((uint2*)xb)[g] = o;
        return;
    }
    blk -= 6144;
    const float* W;
    short* Wt;
    int N, permute, bx, by;
    if (blk < 1728) { W = Wqkv; Wt = Wqt; N = QKVN; permute = 1; bx = blk % 72; by = blk / 72; }
    else { blk -= 1728; W = Wout; Wt = Wot; N = DIM; permute = 0; bx = blk % 24; by = blk / 24; }

    int n0 = bx * 32, k0 = by * 32;
    int c = threadIdx.x & 31, r0 = threadIdx.x >> 5;
    for (int r = r0; r < 32; r += 8)
        T[r][c] = rne16(W[(size_t)(k0 + r) * N + n0 + c]);
    __syncthreads();
    for (int r = r0; r < 32; r += 8) {
        int n = n0 + r;
        int np = n;
        float scale = 1.0f;
        if (permute) {
            int d = n / 36, rem = n - d * 36;
            int which = rem / 12, h = rem - which * 12;
            np = which * 768 + h * 64 + d;
            if (which == 0) scale = QSCALE;
        }
        float v = __bfloat162float(__hip_bfloat16_raw{(unsigned short)T[c][r]});
        Wt[(size_t)np * DIM + k0 + c] = (scale == 1.0f) ? T[c][r] : rne16(v * scale);
    }
}

// ---------------------------------------------------------------------------
// qkv = xb @ Wqkv (via permuted Wqt [2304][768]); glds-staged.
// NEW OUTPUT FORMAT (fragment-linear, for 32x32x16 MFMA consumers):
//   K : per bh, 32 tiles of 64kv x 64d; tile = 8 frags (kt*4+ks) x 1 KB;
//       within frag: lane cl = (kv&31) + 32*((d>>3)&1), 8 shorts = d&7.
//   V^T: per bh, 32 tiles; frag (dt*4+kc); lane cl = (d&31)+32*((kv>>3)&1),
//       8 shorts = kv&7.  (direct store -- no LDS transpose needed)
//   Q : per bh, 16 tiles of 128q x 64d; tile = [group g=q>>5][ks][lane][8],
//       lane cl = (q&31) + 32*((d>>3)&1).
// Consumer ds_reads become base + lane*16 + constant offset (stride-1, free).
// ---------------------------------------------------------------------------
__global__ __launch_bounds__(256) void gemm_qkv(const short* __restrict__ A,
                                                const short* __restrict__ Bt,
                                                short* __restrict__ Qo,
                                                short* __restrict__ Ko,
                                                short* __restrict__ Vto) {
    __shared__ short As[128 * 64];
    __shared__ short Bs[128 * 64];
    const int tid = threadIdx.x;
    const int lane = tid & 63, wave = tid >> 6;
    const int l15 = lane & 15, quad = lane >> 4;

    // XCD swizzle: 8 XCDs x 8 m x 18 n = 1152 blocks
    const int flat = blockIdx.x;
    const int xcd = flat & 7;
    const int local = flat >> 3;
    const int mloc = local & 7, nloc = local >> 3;
    const int m0 = (xcd * 8 + mloc) * 128;
    const int n0 = nloc * 128;

    const int wm = (wave >> 1) * 64, wn = (wave & 1) * 64;
    const int r8 = wave * 8 + (lane >> 3);
    const int c8 = lane & 7;
    const int sc = ((c8 ^ (r8 & 7)) << 3);   // swizzled source chunk (elems)

    const int sn = n0 + wn;                  // wave-uniform output chunk
    const int which = sn / 768;
    const bool swapAB = (which != 2);        // Q/K waves compute C^T

    floatx4 acc[4][4] = {};
    for (int k0 = 0; k0 < DIM; k0 += 64) {
#pragma unroll
        for (int i = 0; i < 4; ++i) {
            int row = i * 32 + r8;
            glds16(&A[(size_t)(m0 + row) * DIM + k0 + sc], &As[(size_t)(i * 32 + wave * 8) * 64]);
            glds16(&Bt[(size_t)(n0 + row) * DIM + k0 + sc], &Bs[(size_t)(i * 32 + wave * 8) * 64]);
        }
        __syncthreads();
#pragma unroll
        for (int ks = 0; ks < 2; ++ks) {
            short8 a[4], b[4];
#pragma unroll
            for (int mt = 0; mt < 4; ++mt)
                a[mt] = *(const short8*)&As[swz8(wm + mt * 16 + l15, ks * 32 + quad * 8)];
#pragma unroll
            for (int nt = 0; nt < 4; ++nt)
                b[nt] = *(const short8*)&Bs[swz8(wn + nt * 16 + l15, ks * 32 + quad * 8)];
            if (swapAB) {
#pragma unroll
                for (int mt = 0; mt < 4; ++mt)
#pragma unroll
                    for (int nt = 0; nt < 4; ++nt)
                        acc[mt][nt] = mfma16(b[nt], a[mt], acc[mt][nt]);
            } else {
#pragma unroll
                for (int mt = 0; mt < 4; ++mt)
#pragma unroll
                    for (int nt = 0; nt < 4; ++nt)
                        acc[mt][nt] = mfma16(a[mt], b[nt], acc[mt][nt]);
            }
        }
        __syncthreads();
    }

    // ---- epilogue: direct stores into fragment-linear tiles ----
    const int h = (sn - which * 768) >> 6;
    const int bb = (m0 + wm) >> 11;

    if (which != 2) {
        // swapped acc: lane covers t = wm + mt*16 + l15, d = nt*16 + quad*4 .. +3
        const bool isQ = (which == 0);
        short* dst = isQ ? Qo : Ko;
        const size_t tb = isQ
            ? ((size_t)(bb * HEADS + h) * 16 + ((m0 & 2047) >> 7)) * 8192
            : ((size_t)(bb * HEADS + h) * 32 + (((m0 + wm) & 2047) >> 6)) * 4096;
#pragma unroll
        for (int mt = 0; mt < 4; ++mt)
#pragma unroll
            for (int nt = 0; nt < 4; ++nt) {
                int cl = (mt & 1) * 16 + l15 + 32 * (quad >> 1);
                int off = isQ
                    ? (((wm >> 5) + (mt >> 1)) * 2048 + nt * 512 + cl * 8 + (quad & 1) * 4)
                    : (((mt >> 1) * 4 + nt) * 512 + cl * 8 + (quad & 1) * 4);
                uint2 pk;
                pk.x = pack2(acc[mt][nt][0], acc[mt][nt][1]);
                pk.y = pack2(acc[mt][nt][2], acc[mt][nt][3]);
                *(uint2*)&dst[tb + off] = pk;
            }
    } else {
        // V (unswapped): lane covers d = nt*16 + l15, kv = wm-rel mt*16 + quad*4 + r
        const size_t tb = ((size_t)(bb * HEADS + h) * 32 + (((m0 + wm) & 2047) >> 6)) * 4096;
#pragma unroll
        for (int mt = 0; mt < 4; ++mt)
#pragma unroll
            for (int nt = 0; nt < 4; ++nt) {
                int cl = (nt & 1) * 16 + l15 + 32 * (quad >> 1);
                int off = ((nt >> 1) * 4 + mt) * 512 + cl * 8 + (quad & 1) * 4;
                uint2 pk;
                pk.x = pack2(acc[mt][nt][0], acc[mt][nt][1]);  // consecutive kv
                pk.y = pack2(acc[mt][nt][2], acc[mt][nt][3]);
                *(uint2*)&Vto[tb + off] = pk;
            }
    }
}

// ---------------------------------------------------------------------------
// MFMA flash attention, 32x32x16 MFMA, fragment-linear tiles:
//   4 waves x 32 q-rows over the full 64-kv tile. FLOP per LDS byte doubles
//   vs the 16x16 version (q_wave 16 -> 32): per-CU LDS read traffic halves
//   (384 -> 192 KB per iter), which was the measured roofline.
//   All ds_reads are base + lane*16 + constant (stride-1, conflict-free,
//   zero per-iter address math). P stays in-register: 32x32 D->B-frag remap
//   is 4 permlane32_swap per S-tile (D col = lane&31 == B col already).
//   K/V double-buffered, 1 barrier/iter, prefetch issued at iter top.
// ---------------------------------------------------------------------------
__global__ __launch_bounds__(256, 3) void attn_mfma(const short* __restrict__ Q,
                                                    const short* __restrict__ K,
                                                    const short* __restrict__ Vt,
                                                    short* __restrict__ O) {
    // [0,16384): K/V double buffer: 2 x (K 4096 | V 4096) shorts = 32 KB
    __shared__ __align__(16) short smem[16384];
    const int tid = threadIdx.x;
    const int lane = tid & 63, wave = tid >> 6;    // 4 waves
    const int l31 = lane & 31, hi = lane >> 5;
    const int flat = blockIdx.x;
    const int xcd = flat & 7, li = flat >> 3;      // li 0..95
    const int bh = xcd + (li % 6) * 8;             // bh % 8 == xcd (K/V L2-local)
    const int q0 = (li / 6) * 128;
    const size_t base = (size_t)bh * SEQ * DHEAD;  // shorts
    const int lane8 = lane * 8;

    // ---- stage Q tile (16 KB fragment-linear) into smem[0..8192) ----
    {
        size_t qtb = base + (size_t)(q0 >> 7) * 8192;
#pragma unroll
        for (int c = 0; c < 4; ++c) {
            int s = wave * 4 + c;
            glds16(&Q[qtb + s * 512 + lane8], &smem[s * 512]);
        }
    }
    __syncthreads();
    short8 qf[4];   // B-frags: q-col = l31 (wave's group), k = d = ks*16+hi*8+e
#pragma unroll
    for (int ks = 0; ks < 4; ++ks)
        qf[ks] = *(const short8*)&smem[wave * 2048 + ks * 512 + lane8];
    __syncthreads();   // Q in regs; smem free for K/V dbuf

    floatx16 o0 = {}, o1 = {};   // O^T rows d = (reg&3)+8*(reg>>2)+4*hi (+32 for o1), col q = l31
    float lsum = 0.f;

    // prologue: stage kv-tile 0 (K 8 KB + V 8 KB, 2+2 segments per wave)
    glds16(&K[base + (2 * wave + 0) * 512 + lane8], &smem[(2 * wave + 0) * 512]);
    glds16(&K[base + (2 * wave + 1) * 512 + lane8], &smem[(2 * wave + 1) * 512]);
    glds16(&Vt[base + (2 * wave + 0) * 512 + lane8], &smem[4096 + (2 * wave + 0) * 512]);
    glds16(&Vt[base + (2 * wave + 1) * 512 + lane8], &smem[4096 + (2 * wave + 1) * 512]);

    for (int t = 0; t < 32; ++t) {
        __syncthreads();          // implicit vmcnt(0): tile t resident; other buf free
        const short* Ks = smem + (t & 1) * 8192;
        const short* Vs = Ks + 4096;
        if (t < 31) {             // prefetch t+1; drains only at NEXT barrier
            size_t ktb = base + (size_t)(t + 1) * 4096;
            short* nb = smem + ((t + 1) & 1) * 8192;
            glds16(&K[ktb + (2 * wave + 0) * 512 + lane8], &nb[(2 * wave + 0) * 512]);
            glds16(&K[ktb + (2 * wave + 1) * 512 + lane8], &nb[(2 * wave + 1) * 512]);
            glds16(&Vt[ktb + (2 * wave + 0) * 512 + lane8], &nb[4096 + (2 * wave + 0) * 512]);
            glds16(&Vt[ktb + (2 * wave + 1) * 512 + lane8], &nb[4096 + (2 * wave + 1) * 512]);
        }

        // ---- S^T = K . Q^T : sa0 = kv 0..31, sa1 = kv 32..63; col q = l31 ----
        floatx16 sa0 = {}, sa1 = {};
        __builtin_amdgcn_s_setprio(1);
#pragma unroll
        for (int ks = 0; ks < 4; ++ks) {
            short8 kf0 = *(const short8*)&Ks[(0 * 4 + ks) * 512 + lane8];
            short8 kf1 = *(const short8*)&Ks[(1 * 4 + ks) * 512 + lane8];
            sa0 = mfma32(kf0, qf[ks], sa0);
            sa1 = mfma32(kf1, qf[ks], sa1);
        }
        __builtin_amdgcn_s_setprio(0);

        // ---- p = exp2(s); pack + permlane32_swap -> PV B-frags (in-register) ----
        // D reg r (=rr+4*blk) holds kv = rr + 8*blk + 4*hi (within its 32-kv tile).
        // B-frag dword j needs kv = hi*8 + 2j (per 16-kv chunk): swap blk pairs
        // across lane halves: P32(pk(blk0), pk(blk1)) -> dwords (j0,j2),(j1,j3).
        short8 pf[4];
#define SOFTPACK(SA, PFA, PFB) {                                              \
        float e0_  = __builtin_amdgcn_exp2f(SA[0]);                           \
        float e1_  = __builtin_amdgcn_exp2f(SA[1]);                           \
        float e2_  = __builtin_amdgcn_exp2f(SA[2]);                           \
        float e3_  = __builtin_amdgcn_exp2f(SA[3]);                           \
        float e4_  = __builtin_amdgcn_exp2f(SA[4]);                           \
        float e5_  = __builtin_amdgcn_exp2f(SA[5]);                           \
        float e6_  = __builtin_amdgcn_exp2f(SA[6]);                           \
        float e7_  = __builtin_amdgcn_exp2f(SA[7]);                           \
        float e8_  = __builtin_amdgcn_exp2f(SA[8]);                           \
        float e9_  = __builtin_amdgcn_exp2f(SA[9]);                           \
        float e10_ = __builtin_amdgcn_exp2f(SA[10]);                          \
        float e11_ = __builtin_amdgcn_exp2f(SA[11]);                          \
        float e12_ = __builtin_amdgcn_exp2f(SA[12]);                          \
        float e13_ = __builtin_amdgcn_exp2f(SA[13]);                          \
        float e14_ = __builtin_amdgcn_exp2f(SA[14]);                          \
        float e15_ = __builtin_amdgcn_exp2f(SA[15]);                          \
        lsum += (((e0_ + e1_) + (e2_ + e3_)) + ((e4_ + e5_) + (e6_ + e7_)))   \
              + (((e8_ + e9_) + (e10_ + e11_)) + ((e12_ + e13_) + (e14_ + e15_))); \
        unsigned A0_ = cvtpk(e0_, e1_),   A1_ = cvtpk(e2_, e3_);              \
        unsigned B0_ = cvtpk(e4_, e5_),   B1_ = cvtpk(e6_, e7_);              \
        unsigned C0_ = cvtpk(e8_, e9_),   C1_ = cvtpk(e10_, e11_);            \
        unsigned E0_ = cvtpk(e12_, e13_), E1_ = cvtpk(e14_, e15_);            \
        asm("v_permlane32_swap_b32 %0, %1" : "+v"(A0_), "+v"(B0_));           \
        asm("v_permlane32_swap_b32 %0, %1" : "+v"(A1_), "+v"(B1_));           \
        asm("v_permlane32_swap_b32 %0, %1" : "+v"(C0_), "+v"(E0_));           \
        asm("v_permlane32_swap_b32 %0, %1" : "+v"(C1_), "+v"(E1_));           \
        uintx4 wa_ = {A0_, A1_, B0_, B1_};                                    \
        uintx4 wb_ = {C0_, C1_, E0_, E1_};                                    \
        PFA = __builtin_bit_cast(short8, wa_);                                \
        PFB = __builtin_bit_cast(short8, wb_);                                \
    }
        SOFTPACK(sa0, pf[0], pf[1])
        SOFTPACK(sa1, pf[2], pf[3])
#undef SOFTPACK

        // ---- O^T += V^T . P^T : A = vf (rows d, k = kv chunk), B = pf ----
        __builtin_amdgcn_s_setprio(1);
#pragma unroll
        for (int kc = 0; kc < 4; ++kc) {
            short8 vf0 = *(const short8*)&Vs[(0 * 4 + kc) * 512 + lane8];
            short8 vf1 = *(const short8*)&Vs[(1 * 4 + kc) * 512 + lane8];
            o0 = mfma32(vf0, pf[kc], o0);
            o1 = mfma32(vf1, pf[kc], o1);
        }
        __builtin_amdgcn_s_setprio(0);
    }

    // ---- epilogue: lane pair (hi^1) holds the other 32 kv -> one xor-32 ----
    float s = lsum + __shfl_xor(lsum, 32);
    float inv = 1.f / s;

    const int b = bh / HEADS, h = bh - b * HEADS;
    const int tq = q0 + wave * 32 + l31;
    size_t rowo = ((size_t)(b * SEQ + tq)) * DIM + h * DHEAD;
#pragma unroll
    for (int blk = 0; blk < 4; ++blk) {
        int d0 = 8 * blk + 4 * hi;
        uint2 p0, p1;
        p0.x = cvtpk(o0[4 * blk + 0] * inv, o0[4 * blk + 1] * inv);
        p0.y = cvtpk(o0[4 * blk + 2] * inv, o0[4 * blk + 3] * inv);
        *(uint2*)&O[rowo + d0] = p0;
        p1.x = cvtpk(o1[4 * blk + 0] * inv, o1[4 * blk + 1] * inv);
        p1.y = cvtpk(o1[4 * blk + 2] * inv, o1[4 * blk + 3] * inv);
        *(uint2*)&O[rowo + 32 + d0] = p1;
    }
}

// ---------------------------------------------------------------------------
// out = attnB @ Wout (via Wot [768][768]), fp32 output; glds-staged.
// All waves SWAP operands (C^T): lane holds 4 consecutive n at fixed m ->
// one dwordx4 store per acc (16/lane, not 64 scalar dwords).
// ---------------------------------------------------------------------------
__global__ __launch_bounds__(256) void gemm_out(const short* __restrict__ A,
                                                const short* __restrict__ Bt,
                                                float* __restrict__ out) {
    __shared__ short As[128 * 64];
    __shared__ short Bs[128 * 64];
    const int tid = threadIdx.x;
    const int lane = tid & 63, wave = tid >> 6;
    const int l15 = lane & 15, quad = lane >> 4;
    const int m0 = blockIdx.y * 128, n0 = blockIdx.x * 128;
    const int wm = (wave >> 1) * 64, wn = (wave & 1) * 64;
    const int r8 = wave * 8 + (lane >> 3);
    const int sc = (((lane & 7) ^ (r8 & 7)) << 3);

    floatx4 acc[4][4] = {};
    for (int k0 = 0; k0 < DIM; k0 += 64) {
#pragma unroll
        for (int i = 0; i < 4; ++i) {
            int row = i * 32 + r8;
            glds16(&A[(size_t)(m0 + row) * DIM + k0 + sc], &As[(size_t)(i * 32 + wave * 8) * 64]);
            glds16(&Bt[(size_t)(n0 + row) * DIM + k0 + sc], &Bs[(size_t)(i * 32 + wave * 8) * 64]);
        }
        __syncthreads();
#pragma unroll
        for (int ks = 0; ks < 2; ++ks) {
            short8 a[4], b[4];
#pragma unroll
            for (int mt = 0; mt < 4; ++mt)
                a[mt] = *(const short8*)&As[swz8(wm + mt * 16 + l15, ks * 32 + quad * 8)];
#pragma unroll
            for (int nt = 0; nt < 4; ++nt)
                b[nt] = *(const short8*)&Bs[swz8(wn + nt * 16 + l15, ks * 32 + quad * 8)];
#pragma unroll
            for (int mt = 0; mt < 4; ++mt)
#pragma unroll
                for (int nt = 0; nt < 4; ++nt)
                    acc[mt][nt] = mfma16(b[nt], a[mt], acc[mt][nt]);  // C^T
        }
        __syncthreads();
    }

    // swapped: m = wm+mt*16+l15, n = wn+nt*16+quad*4..+3 -> dwordx4 stores
#pragma unroll
    for (int mt = 0; mt < 4; ++mt)
#pragma unroll
        for (int nt = 0; nt < 4; ++nt) {
            int m = m0 + wm + mt * 16 + l15;
            int n = n0 + wn + nt * 16 + quad * 4;
            *(floatx4*)&out[(size_t)m * DIM + n] = acc[mt][nt];
        }
}

// ---------------------------------------------------------------------------
extern "C" void kernel_launch(void* const* d_in, const int* in_sizes, int n_in,
                              void* d_out, int out_size, void* d_ws, size_t ws_size,
                              hipStream_t stream) {
    const float* x    = (const float*)d_in[0];  // [4,2048,768] fp32
    const float* Wqkv = (const float*)d_in[1];  // [768,2304]  fp32
    const float* Wout = (const float*)d_in[2];  // [768,768]   fp32
    float* out = (float*)d_out;                 // [4,2048,768] fp32

    const size_t NE = (size_t)NROW * DIM;       // 6291456
    short* xb  = (short*)d_ws;                  // x bf16; later reused as attnB
    short* Wqt = xb + NE;                       // [2304][768] (col-permuted, Q-rows pre-scaled)
    short* Wot = Wqt + (size_t)QKVN * DIM;      // [768][768]
    short* Qw  = Wot + (size_t)DIM * DIM;       // fragment-linear 128q tiles
    short* Kw  = Qw + NE;                       // fragment-linear 64kv tiles
    short* Vtw = Kw + NE;                       // fragment-linear V^T tiles

    prep<<<6144 + 1728 + 576, 256, 0, stream>>>(x, xb, Wqkv, Wqt, Wout, Wot);
    gemm_qkv<<<8 * 8 * 18, 256, 0, stream>>>(xb, Wqt, Qw, Kw, Vtw);
    // xb (x in bf16) is dead after gemm_qkv -> reuse as attention output buffer
    attn_mfma<<<768, 256, 0, stream>>>(Qw, Kw, Vtw, xb);
    gemm_out<<<dim3(DIM / 128, NROW / 128), 256, 0, stream>>>(xb, Wot, out);
}

// Round 5
// 207.508 us; speedup vs baseline: 1.0179x; 1.0124x over previous
//
#include <hip/hip_runtime.h>
#include <hip/hip_bf16.h>

#define DIM    768
#define HEADS  12
#define DHEAD  64
#define BATCH  4
#define SEQ    2048
#define NROW   (BATCH * SEQ)   // 8192
#define QKVN   (3 * DIM)       // 2304
#define FACTOR 0.125f          // 64^-0.5
#define QSCALE 0.18033688011112042f  // FACTOR * log2(e), folded into Wqt rows <768

typedef __attribute__((ext_vector_type(8))) short short8;    // 8 bf16 = 4 VGPR
typedef __attribute__((ext_vector_type(4))) float floatx4;   // 16x16 C/D
typedef __attribute__((ext_vector_type(16))) float floatx16; // 32x32 C/D
typedef __attribute__((ext_vector_type(4))) unsigned uintx4;

__device__ __forceinline__ floatx4 mfma16(short8 a, short8 b, floatx4 c) {
    return __builtin_amdgcn_mfma_f32_16x16x32_bf16(a, b, c, 0, 0, 0);
}
__device__ __forceinline__ floatx16 mfma32(short8 a, short8 b, floatx16 c) {
    return __builtin_amdgcn_mfma_f32_32x32x16_bf16(a, b, c, 0, 0, 0);
}

// async global->LDS, 16B per lane; lds base must be wave-uniform,
// deposits at base + lane*16 (lane-ordered source REQUIRED for coalescing)
__device__ __forceinline__ void glds16(const void* g, void* l) {
    __builtin_amdgcn_global_load_lds((const __attribute__((address_space(1))) void*)g,
                                     (__attribute__((address_space(3))) void*)l,
                                     16, 0, 0);
}

// branchless RNE fp32->bf16 (finite values only)
__device__ __forceinline__ short rne16(float f) {
    unsigned u = __builtin_bit_cast(unsigned, f);
    return (short)((u + 0x7fffu + ((u >> 16) & 1u)) >> 16);
}
__device__ __forceinline__ unsigned pack2(float lo, float hi) {
    unsigned ul = __builtin_bit_cast(unsigned, lo);
    unsigned uh = __builtin_bit_cast(unsigned, hi);
    ul = (ul + 0x7fffu + ((ul >> 16) & 1u)) >> 16;
    uh = (uh + 0x7fffu + ((uh >> 16) & 1u)) & 0xffff0000u;
    return ul | uh;
}
// HW packed RNE cvt (gfx950): lo -> bits[15:0], hi -> bits[31:16]
__device__ __forceinline__ unsigned cvtpk(float lo, float hi) {
    unsigned r;
    asm("v_cvt_pk_bf16_f32 %0, %1, %2" : "=v"(r) : "v"(lo), "v"(hi));
    return r;
}

// XOR-swizzled tile addressing (still used by the GEMM LDS staging paths)
__device__ __forceinline__ int swz8(int row, int col) {
    return (row << 6) + ((((col >> 3) ^ row) & 7) << 3) + (col & 7);
}

// ---------------------------------------------------------------------------
// prep (fused): blocks [0,6144)   : x fp32 -> bf16
//               blocks [6144,7872): Wqkv transpose+permute (+QSCALE rows<768)
//               blocks [7872,8448): Wout transpose
// ---------------------------------------------------------------------------
__global__ __launch_bounds__(256) void prep(const float* __restrict__ x,
                                            short* __restrict__ xb,
                                            const float* __restrict__ Wqkv,
                                            short* __restrict__ Wqt,
                                            const float* __restrict__ Wout,
                                            short* __restrict__ Wot) {
    __shared__ short T[32][33];
    int blk = blockIdx.x;
    if (blk < 6144) {
        int g = blk * 256 + threadIdx.x;
        float4 v = ((const float4*)x)[g];
        uint2 o;
        o.x = pack2(v.x, v.y);
        o.y = pack2(v.z, v.w);
        ((uint2*)xb)[g] = o;
        return;
    }
    blk -= 6144;
    const float* W;
    short* Wt;
    int N, permute, bx, by;
    if (blk < 1728) { W = Wqkv; Wt = Wqt; N = QKVN; permute = 1; bx = blk % 72; by = blk / 72; }
    else { blk -= 1728; W = Wout; Wt = Wot; N = DIM; permute = 0; bx = blk % 24; by = blk / 24; }

    int n0 = bx * 32, k0 = by * 32;
    int c = threadIdx.x & 31, r0 = threadIdx.x >> 5;
    for (int r = r0; r < 32; r += 8)
        T[r][c] = rne16(W[(size_t)(k0 + r) * N + n0 + c]);
    __syncthreads();
    for (int r = r0; r < 32; r += 8) {
        int n = n0 + r;
        int np = n;
        float scale = 1.0f;
        if (permute) {
            int d = n / 36, rem = n - d * 36;
            int which = rem / 12, h = rem - which * 12;
            np = which * 768 + h * 64 + d;
            if (which == 0) scale = QSCALE;
        }
        float v = __bfloat162float(__hip_bfloat16_raw{(unsigned short)T[c][r]});
        Wt[(size_t)np * DIM + k0 + c] = (scale == 1.0f) ? T[c][r] : rne16(v * scale);
    }
}

// ---------------------------------------------------------------------------
// qkv = xb @ Wqkv (via permuted Wqt [2304][768]); glds-staged.
// Fragment-linear outputs for the 32x32x16 attention consumer (see R4 notes).
// ---------------------------------------------------------------------------
__global__ __launch_bounds__(256) void gemm_qkv(const short* __restrict__ A,
                                                const short* __restrict__ Bt,
                                                short* __restrict__ Qo,
                                                short* __restrict__ Ko,
                                                short* __restrict__ Vto) {
    __shared__ short As[128 * 64];
    __shared__ short Bs[128 * 64];
    const int tid = threadIdx.x;
    const int lane = tid & 63, wave = tid >> 6;
    const int l15 = lane & 15, quad = lane >> 4;

    // XCD swizzle: 8 XCDs x 8 m x 18 n = 1152 blocks
    const int flat = blockIdx.x;
    const int xcd = flat & 7;
    const int local = flat >> 3;
    const int mloc = local & 7, nloc = local >> 3;
    const int m0 = (xcd * 8 + mloc) * 128;
    const int n0 = nloc * 128;

    const int wm = (wave >> 1) * 64, wn = (wave & 1) * 64;
    const int r8 = wave * 8 + (lane >> 3);
    const int c8 = lane & 7;
    const int sc = ((c8 ^ (r8 & 7)) << 3);   // swizzled source chunk (elems)

    const int sn = n0 + wn;                  // wave-uniform output chunk
    const int which = sn / 768;
    const bool swapAB = (which != 2);        // Q/K waves compute C^T

    floatx4 acc[4][4] = {};
    for (int k0 = 0; k0 < DIM; k0 += 64) {
#pragma unroll
        for (int i = 0; i < 4; ++i) {
            int row = i * 32 + r8;
            glds16(&A[(size_t)(m0 + row) * DIM + k0 + sc], &As[(size_t)(i * 32 + wave * 8) * 64]);
            glds16(&Bt[(size_t)(n0 + row) * DIM + k0 + sc], &Bs[(size_t)(i * 32 + wave * 8) * 64]);
        }
        __syncthreads();
#pragma unroll
        for (int ks = 0; ks < 2; ++ks) {
            short8 a[4], b[4];
#pragma unroll
            for (int mt = 0; mt < 4; ++mt)
                a[mt] = *(const short8*)&As[swz8(wm + mt * 16 + l15, ks * 32 + quad * 8)];
#pragma unroll
            for (int nt = 0; nt < 4; ++nt)
                b[nt] = *(const short8*)&Bs[swz8(wn + nt * 16 + l15, ks * 32 + quad * 8)];
            if (swapAB) {
#pragma unroll
                for (int mt = 0; mt < 4; ++mt)
#pragma unroll
                    for (int nt = 0; nt < 4; ++nt)
                        acc[mt][nt] = mfma16(b[nt], a[mt], acc[mt][nt]);
            } else {
#pragma unroll
                for (int mt = 0; mt < 4; ++mt)
#pragma unroll
                    for (int nt = 0; nt < 4; ++nt)
                        acc[mt][nt] = mfma16(a[mt], b[nt], acc[mt][nt]);
            }
        }
        __syncthreads();
    }

    // ---- epilogue: direct stores into fragment-linear tiles ----
    const int h = (sn - which * 768) >> 6;
    const int bb = (m0 + wm) >> 11;

    if (which != 2) {
        // swapped acc: lane covers t = wm + mt*16 + l15, d = nt*16 + quad*4 .. +3
        const bool isQ = (which == 0);
        short* dst = isQ ? Qo : Ko;
        const size_t tb = isQ
            ? ((size_t)(bb * HEADS + h) * 16 + ((m0 & 2047) >> 7)) * 8192
            : ((size_t)(bb * HEADS + h) * 32 + (((m0 + wm) & 2047) >> 6)) * 4096;
#pragma unroll
        for (int mt = 0; mt < 4; ++mt)
#pragma unroll
            for (int nt = 0; nt < 4; ++nt) {
                int cl = (mt & 1) * 16 + l15 + 32 * (quad >> 1);
                int off = isQ
                    ? (((wm >> 5) + (mt >> 1)) * 2048 + nt * 512 + cl * 8 + (quad & 1) * 4)
                    : (((mt >> 1) * 4 + nt) * 512 + cl * 8 + (quad & 1) * 4);
                uint2 pk;
                pk.x = pack2(acc[mt][nt][0], acc[mt][nt][1]);
                pk.y = pack2(acc[mt][nt][2], acc[mt][nt][3]);
                *(uint2*)&dst[tb + off] = pk;
            }
    } else {
        // V (unswapped): lane covers d = nt*16 + l15, kv = wm-rel mt*16 + quad*4 + r
        const size_t tb = ((size_t)(bb * HEADS + h) * 32 + (((m0 + wm) & 2047) >> 6)) * 4096;
#pragma unroll
        for (int mt = 0; mt < 4; ++mt)
#pragma unroll
            for (int nt = 0; nt < 4; ++nt) {
                int cl = (nt & 1) * 16 + l15 + 32 * (quad >> 1);
                int off = ((nt >> 1) * 4 + mt) * 512 + cl * 8 + (quad & 1) * 4;
                uint2 pk;
                pk.x = pack2(acc[mt][nt][0], acc[mt][nt][1]);  // consecutive kv
                pk.y = pack2(acc[mt][nt][2], acc[mt][nt][3]);
                *(uint2*)&Vto[tb + off] = pk;
            }
    }
}

// ---------------------------------------------------------------------------
// MFMA flash attention, 32x32x16, fragment-linear tiles, T15 pipelined:
//   4 waves x 32 q-rows over the full 64-kv tile.
//   - pf(t-1) carried in regs; PV(t-1) issues RIGHT AFTER QK(t)'s MFMAs ->
//     16 back-to-back independent MFMA issues/iter, and sm(t)'s exp2/pack
//     VALU overlaps PV(t-1) MFMA execution (breaks phase alignment).
//   - 3-deep K/V LDS buffers (V(t-1) must outlive iter t's prefetch).
//     WAR-safe: prefetch(t+1) -> buf[(t+1)%3], last read at iter t-1,
//     covered by iter t's barrier. 1 barrier/iter, depth-1 prefetch.
//   - all ds_reads are base + lane*16 + constant (conflict-free, no addr math)
// ---------------------------------------------------------------------------
__global__ __launch_bounds__(256, 3) void attn_mfma(const short* __restrict__ Q,
                                                    const short* __restrict__ K,
                                                    const short* __restrict__ Vt,
                                                    short* __restrict__ O) {
    // 3 buffers x (K 4096 | V 4096) shorts = 48 KB
    __shared__ __align__(16) short smem[24576];
    const int tid = threadIdx.x;
    const int lane = tid & 63, wave = tid >> 6;    // 4 waves
    const int l31 = lane & 31, hi = lane >> 5;
    const int flat = blockIdx.x;
    const int xcd = flat & 7, li = flat >> 3;      // li 0..95
    const int bh = xcd + (li % 6) * 8;             // bh % 8 == xcd (K/V L2-local)
    const int q0 = (li / 6) * 128;
    const size_t base = (size_t)bh * SEQ * DHEAD;  // shorts
    const int lane8 = lane * 8;

    // ---- stage Q tile (16 KB fragment-linear) into smem[0..8192) ----
    {
        size_t qtb = base + (size_t)(q0 >> 7) * 8192;
#pragma unroll
        for (int c = 0; c < 4; ++c) {
            int s = wave * 4 + c;
            glds16(&Q[qtb + s * 512 + lane8], &smem[s * 512]);
        }
    }
    __syncthreads();
    short8 qf[4];   // B-frags: q-col = l31 (wave's group), k = d = ks*16+hi*8+e
#pragma unroll
    for (int ks = 0; ks < 4; ++ks)
        qf[ks] = *(const short8*)&smem[wave * 2048 + ks * 512 + lane8];
    __syncthreads();   // Q in regs; smem free for K/V buffers

    floatx16 o0 = {}, o1 = {};   // O^T rows d = (reg&3)+8*(reg>>2)+4*hi (+32 for o1), col q = l31
    float lsum = 0.f;

    const int seg0 = (2 * wave + 0) * 512;   // this wave's staging segments
    const int seg1 = (2 * wave + 1) * 512;

#define STAGE(tt, buf) {                                                \
        size_t ktb_ = base + (size_t)(tt) * 4096;                       \
        glds16(&K[ktb_ + seg0 + lane8], &(buf)[seg0]);                  \
        glds16(&K[ktb_ + seg1 + lane8], &(buf)[seg1]);                  \
        glds16(&Vt[ktb_ + seg0 + lane8], &(buf)[4096 + seg0]);          \
        glds16(&Vt[ktb_ + seg1 + lane8], &(buf)[4096 + seg1]);          \
    }

    // p = exp2(s); pack + permlane32_swap -> PV B-frags (in-register).
    // D reg r (=rr+4*blk) holds kv = rr + 8*blk + 4*hi (within its 32-kv tile);
    // B-frag dword j needs kv = hi*8 + 2j per 16-kv chunk: P32-swap blk pairs.
#define SOFTPACK(SA, PFA, PFB) {                                              \
        float e0_  = __builtin_amdgcn_exp2f(SA[0]);                           \
        float e1_  = __builtin_amdgcn_exp2f(SA[1]);                           \
        float e2_  = __builtin_amdgcn_exp2f(SA[2]);                           \
        float e3_  = __builtin_amdgcn_exp2f(SA[3]);                           \
        float e4_  = __builtin_amdgcn_exp2f(SA[4]);                           \
        float e5_  = __builtin_amdgcn_exp2f(SA[5]);                           \
        float e6_  = __builtin_amdgcn_exp2f(SA[6]);                           \
        float e7_  = __builtin_amdgcn_exp2f(SA[7]);                           \
        float e8_  = __builtin_amdgcn_exp2f(SA[8]);                           \
        float e9_  = __builtin_amdgcn_exp2f(SA[9]);                           \
        float e10_ = __builtin_amdgcn_exp2f(SA[10]);                          \
        float e11_ = __builtin_amdgcn_exp2f(SA[11]);                          \
        float e12_ = __builtin_amdgcn_exp2f(SA[12]);                          \
        float e13_ = __builtin_amdgcn_exp2f(SA[13]);                          \
        float e14_ = __builtin_amdgcn_exp2f(SA[14]);                          \
        float e15_ = __builtin_amdgcn_exp2f(SA[15]);                          \
        lsum += (((e0_ + e1_) + (e2_ + e3_)) + ((e4_ + e5_) + (e6_ + e7_)))   \
              + (((e8_ + e9_) + (e10_ + e11_)) + ((e12_ + e13_) + (e14_ + e15_))); \
        unsigned A0_ = cvtpk(e0_, e1_),   A1_ = cvtpk(e2_, e3_);              \
        unsigned B0_ = cvtpk(e4_, e5_),   B1_ = cvtpk(e6_, e7_);              \
        unsigned C0_ = cvtpk(e8_, e9_),   C1_ = cvtpk(e10_, e11_);            \
        unsigned E0_ = cvtpk(e12_, e13_), E1_ = cvtpk(e14_, e15_);            \
        asm("v_permlane32_swap_b32 %0, %1" : "+v"(A0_), "+v"(B0_));           \
        asm("v_permlane32_swap_b32 %0, %1" : "+v"(A1_), "+v"(B1_));           \
        asm("v_permlane32_swap_b32 %0, %1" : "+v"(C0_), "+v"(E0_));           \
        asm("v_permlane32_swap_b32 %0, %1" : "+v"(C1_), "+v"(E1_));           \
        uintx4 wa_ = {A0_, A1_, B0_, B1_};                                    \
        uintx4 wb_ = {C0_, C1_, E0_, E1_};                                    \
        PFA = __builtin_bit_cast(short8, wa_);                                \
        PFB = __builtin_bit_cast(short8, wb_);                                \
    }

#define QK(Ks, SA0, SA1) {                                                    \
        __builtin_amdgcn_s_setprio(1);                                        \
        _Pragma("unroll")                                                     \
        for (int ks_ = 0; ks_ < 4; ++ks_) {                                   \
            short8 kf0_ = *(const short8*)&(Ks)[(0 * 4 + ks_) * 512 + lane8]; \
            short8 kf1_ = *(const short8*)&(Ks)[(1 * 4 + ks_) * 512 + lane8]; \
            SA0 = mfma32(kf0_, qf[ks_], SA0);                                 \
            SA1 = mfma32(kf1_, qf[ks_], SA1);                                 \
        }                                                                     \
        __builtin_amdgcn_s_setprio(0);                                        \
    }

#define PV(Vs, PF) {                                                          \
        __builtin_amdgcn_s_setprio(1);                                        \
        _Pragma("unroll")                                                     \
        for (int kc_ = 0; kc_ < 4; ++kc_) {                                   \
            short8 vf0_ = *(const short8*)&(Vs)[(0 * 4 + kc_) * 512 + lane8]; \
            short8 vf1_ = *(const short8*)&(Vs)[(1 * 4 + kc_) * 512 + lane8]; \
            o0 = mfma32(vf0_, PF[kc_], o0);                                   \
            o1 = mfma32(vf1_, PF[kc_], o1);                                   \
        }                                                                     \
        __builtin_amdgcn_s_setprio(0);                                        \
    }

    short8 pfp[4];   // pf(t-1) carry

    // prologue: stage tile 0 -> buf0
    STAGE(0, smem);
    // ---- t = 0 peel: QK + softmax only (no PV yet) ----
    {
        __syncthreads();               // tile 0 resident
        STAGE(1, smem + 8192);         // prefetch tile 1 -> buf1
        floatx16 sa0 = {}, sa1 = {};
        QK(smem, sa0, sa1);
        SOFTPACK(sa0, pfp[0], pfp[1])
        SOFTPACK(sa1, pfp[2], pfp[3])
    }

    int bp = 0, bc = 1, bn = 2;
    for (int t = 1; t < 32; ++t) {
        __syncthreads();               // tile t resident; buf[bn] free
        short* curb = smem + bc * 8192;
        short* prvb = smem + bp * 8192;
        if (t < 31)
            STAGE(t + 1, smem + bn * 8192);

        // QK(t) then PV(t-1): 16 independent MFMA issues back-to-back;
        // sm(t) VALU below overlaps PV's MFMA execution.
        floatx16 sa0 = {}, sa1 = {};
        QK(curb, sa0, sa1);
        PV(prvb + 4096, pfp);

        short8 pfc[4];
        SOFTPACK(sa0, pfc[0], pfc[1])
        SOFTPACK(sa1, pfc[2], pfc[3])
#pragma unroll
        for (int i = 0; i < 4; ++i) pfp[i] = pfc[i];

        // rotate buffers
        bp = bc; bc = bn; bn = (bn == 2) ? 0 : bn + 1;
    }
    // final PV for tile 31 (its buffer is bp after the last rotate)
    PV(smem + bp * 8192 + 4096, pfp);

#undef QK
#undef PV
#undef SOFTPACK
#undef STAGE

    // ---- epilogue: lane pair (hi^1) holds the other 32 kv -> one xor-32 ----
    float s = lsum + __shfl_xor(lsum, 32);
    float inv = 1.f / s;

    const int b = bh / HEADS, h = bh - b * HEADS;
    const int tq = q0 + wave * 32 + l31;
    size_t rowo = ((size_t)(b * SEQ + tq)) * DIM + h * DHEAD;
#pragma unroll
    for (int blk = 0; blk < 4; ++blk) {
        int d0 = 8 * blk + 4 * hi;
        uint2 p0, p1;
        p0.x = cvtpk(o0[4 * blk + 0] * inv, o0[4 * blk + 1] * inv);
        p0.y = cvtpk(o0[4 * blk + 2] * inv, o0[4 * blk + 3] * inv);
        *(uint2*)&O[rowo + d0] = p0;
        p1.x = cvtpk(o1[4 * blk + 0] * inv, o1[4 * blk + 1] * inv);
        p1.y = cvtpk(o1[4 * blk + 2] * inv, o1[4 * blk + 3] * inv);
        *(uint2*)&O[rowo + 32 + d0] = p1;
    }
}

// ---------------------------------------------------------------------------
// out = attnB @ Wout (via Wot [768][768]), fp32 output; glds-staged.
// Retiled 64x128 (was 128x128): grid 768 = 3.0 blocks/CU even (was 384 =
// 1.5/CU -> half the CUs ran two serial blocks). 12 waves/CU.
// All waves SWAP operands (C^T) -> dwordx4 stores.
// ---------------------------------------------------------------------------
__global__ __launch_bounds__(256) void gemm_out(const short* __restrict__ A,
                                                const short* __restrict__ Bt,
                                                float* __restrict__ out) {
    __shared__ short As[64 * 64];
    __shared__ short Bs[128 * 64];
    const int tid = threadIdx.x;
    const int lane = tid & 63, wave = tid >> 6;
    const int l15 = lane & 15, quad = lane >> 4;
    const int m0 = blockIdx.y * 64, n0 = blockIdx.x * 128;
    const int wn = wave * 32;                 // wave's 32-col slice; rows shared
    const int r8 = wave * 8 + (lane >> 3);
    const int sc = (((lane & 7) ^ (r8 & 7)) << 3);

    floatx4 acc[4][2] = {};
    for (int k0 = 0; k0 < DIM; k0 += 64) {
#pragma unroll
        for (int i = 0; i < 2; ++i) {
            int row = i * 32 + r8;
            glds16(&A[(size_t)(m0 + row) * DIM + k0 + sc], &As[(size_t)(i * 32 + wave * 8) * 64]);
        }
#pragma unroll
        for (int i = 0; i < 4; ++i) {
            int row = i * 32 + r8;
            glds16(&Bt[(size_t)(n0 + row) * DIM + k0 + sc], &Bs[(size_t)(i * 32 + wave * 8) * 64]);
        }
        __syncthreads();
#pragma unroll
        for (int ks = 0; ks < 2; ++ks) {
            short8 a[4], b[2];
#pragma unroll
            for (int mt = 0; mt < 4; ++mt)
                a[mt] = *(const short8*)&As[swz8(mt * 16 + l15, ks * 32 + quad * 8)];
#pragma unroll
            for (int nt = 0; nt < 2; ++nt)
                b[nt] = *(const short8*)&Bs[swz8(wn + nt * 16 + l15, ks * 32 + quad * 8)];
#pragma unroll
            for (int mt = 0; mt < 4; ++mt)
#pragma unroll
                for (int nt = 0; nt < 2; ++nt)
                    acc[mt][nt] = mfma16(b[nt], a[mt], acc[mt][nt]);  // C^T
        }
        __syncthreads();
    }

    // swapped: m = mt*16+l15, n = wn+nt*16+quad*4..+3 -> dwordx4 stores
#pragma unroll
    for (int mt = 0; mt < 4; ++mt)
#pragma unroll
        for (int nt = 0; nt < 2; ++nt) {
            int m = m0 + mt * 16 + l15;
            int n = n0 + wn + nt * 16 + quad * 4;
            *(floatx4*)&out[(size_t)m * DIM + n] = acc[mt][nt];
        }
}

// ---------------------------------------------------------------------------
extern "C" void kernel_launch(void* const* d_in, const int* in_sizes, int n_in,
                              void* d_out, int out_size, void* d_ws, size_t ws_size,
                              hipStream_t stream) {
    const float* x    = (const float*)d_in[0];  // [4,2048,768] fp32
    const float* Wqkv = (const float*)d_in[1];  // [768,2304]  fp32
    const float* Wout = (const float*)d_in[2];  // [768,768]   fp32
    float* out = (float*)d_out;                 // [4,2048,768] fp32

    const size_t NE = (size_t)NROW * DIM;       // 6291456
    short* xb  = (short*)d_ws;                  // x bf16; later reused as attnB
    short* Wqt = xb + NE;                       // [2304][768] (col-permuted, Q-rows pre-scaled)
    short* Wot = Wqt + (size_t)QKVN * DIM;      // [768][768]
    short* Qw  = Wot + (size_t)DIM * DIM;       // fragment-linear 128q tiles
    short* Kw  = Qw + NE;                       // fragment-linear 64kv tiles
    short* Vtw = Kw + NE;                       // fragment-linear V^T tiles

    prep<<<6144 + 1728 + 576, 256, 0, stream>>>(x, xb, Wqkv, Wqt, Wout, Wot);
    gemm_qkv<<<8 * 8 * 18, 256, 0, stream>>>(xb, Wqt, Qw, Kw, Vtw);
    // xb (x in bf16) is dead after gemm_qkv -> reuse as attention output buffer
    attn_mfma<<<768, 256, 0, stream>>>(Qw, Kw, Vtw, xb);
    gemm_out<<<dim3(DIM / 128, NROW / 64), 256, 0, stream>>>(xb, Wot, out);
}

// Round 6
// 205.154 us; speedup vs baseline: 1.0296x; 1.0115x over previous
//
#include <hip/hip_runtime.h>
#include <hip/hip_bf16.h>

#define DIM    768
#define HEADS  12
#define DHEAD  64
#define BATCH  4
#define SEQ    2048
#define NROW   (BATCH * SEQ)   // 8192
#define QKVN   (3 * DIM)       // 2304
#define FACTOR 0.125f          // 64^-0.5
#define QSCALE 0.18033688011112042f  // FACTOR * log2(e), folded into Wqt rows <768

typedef __attribute__((ext_vector_type(8))) short short8;    // 8 bf16 = 4 VGPR
typedef __attribute__((ext_vector_type(4))) float floatx4;   // 16x16 C/D
typedef __attribute__((ext_vector_type(16))) float floatx16; // 32x32 C/D
typedef __attribute__((ext_vector_type(4))) unsigned uintx4;

__device__ __forceinline__ floatx4 mfma16(short8 a, short8 b, floatx4 c) {
    return __builtin_amdgcn_mfma_f32_16x16x32_bf16(a, b, c, 0, 0, 0);
}
__device__ __forceinline__ floatx16 mfma32(short8 a, short8 b, floatx16 c) {
    return __builtin_amdgcn_mfma_f32_32x32x16_bf16(a, b, c, 0, 0, 0);
}

// async global->LDS, 16B per lane; lds base must be wave-uniform,
// deposits at base + lane*16 (lane-ordered source REQUIRED for coalescing)
__device__ __forceinline__ void glds16(const void* g, void* l) {
    __builtin_amdgcn_global_load_lds((const __attribute__((address_space(1))) void*)g,
                                     (__attribute__((address_space(3))) void*)l,
                                     16, 0, 0);
}

// branchless RNE fp32->bf16 (finite values only)
__device__ __forceinline__ short rne16(float f) {
    unsigned u = __builtin_bit_cast(unsigned, f);
    return (short)((u + 0x7fffu + ((u >> 16) & 1u)) >> 16);
}
__device__ __forceinline__ unsigned pack2(float lo, float hi) {
    unsigned ul = __builtin_bit_cast(unsigned, lo);
    unsigned uh = __builtin_bit_cast(unsigned, hi);
    ul = (ul + 0x7fffu + ((ul >> 16) & 1u)) >> 16;
    uh = (uh + 0x7fffu + ((uh >> 16) & 1u)) & 0xffff0000u;
    return ul | uh;
}
// HW packed RNE cvt (gfx950): lo -> bits[15:0], hi -> bits[31:16]
__device__ __forceinline__ unsigned cvtpk(float lo, float hi) {
    unsigned r;
    asm("v_cvt_pk_bf16_f32 %0, %1, %2" : "=v"(r) : "v"(lo), "v"(hi));
    return r;
}

// XOR-swizzled tile addressing (still used by the GEMM LDS staging paths)
__device__ __forceinline__ int swz8(int row, int col) {
    return (row << 6) + ((((col >> 3) ^ row) & 7) << 3) + (col & 7);
}

// ---------------------------------------------------------------------------
// prep (fused): blocks [0,6144)   : x fp32 -> bf16
//               blocks [6144,7872): Wqkv transpose+permute (+QSCALE rows<768)
//               blocks [7872,8448): Wout transpose
// ---------------------------------------------------------------------------
__global__ __launch_bounds__(256) void prep(const float* __restrict__ x,
                                            short* __restrict__ xb,
                                            const float* __restrict__ Wqkv,
                                            short* __restrict__ Wqt,
                                            const float* __restrict__ Wout,
                                            short* __restrict__ Wot) {
    __shared__ short T[32][33];
    int blk = blockIdx.x;
    if (blk < 6144) {
        int g = blk * 256 + threadIdx.x;
        float4 v = ((const float4*)x)[g];
        uint2 o;
        o.x = pack2(v.x, v.y);
        o.y = pack2(v.z, v.w);
        ((uint2*)xb)[g] = o;
        return;
    }
    blk -= 6144;
    const float* W;
    short* Wt;
    int N, permute, bx, by;
    if (blk < 1728) { W = Wqkv; Wt = Wqt; N = QKVN; permute = 1; bx = blk % 72; by = blk / 72; }
    else { blk -= 1728; W = Wout; Wt = Wot; N = DIM; permute = 0; bx = blk % 24; by = blk / 24; }

    int n0 = bx * 32, k0 = by * 32;
    int c = threadIdx.x & 31, r0 = threadIdx.x >> 5;
    for (int r = r0; r < 32; r += 8)
        T[r][c] = rne16(W[(size_t)(k0 + r) * N + n0 + c]);
    __syncthreads();
    for (int r = r0; r < 32; r += 8) {
        int n = n0 + r;
        int np = n;
        float scale = 1.0f;
        if (permute) {
            int d = n / 36, rem = n - d * 36;
            int which = rem / 12, h = rem - which * 12;
            np = which * 768 + h * 64 + d;
            if (which == 0) scale = QSCALE;
        }
        float v = __bfloat162float(__hip_bfloat16_raw{(unsigned short)T[c][r]});
        Wt[(size_t)np * DIM + k0 + c] = (scale == 1.0f) ? T[c][r] : rne16(v * scale);
    }
}

// ---------------------------------------------------------------------------
// qkv = xb @ Wqkv (via permuted Wqt [2304][768]); glds-staged.
// Fragment-linear outputs for the 32x32x16 attention consumer (see R4 notes).
// ---------------------------------------------------------------------------
__global__ __launch_bounds__(256) void gemm_qkv(const short* __restrict__ A,
                                                const short* __restrict__ Bt,
                                                short* __restrict__ Qo,
                                                short* __restrict__ Ko,
                                                short* __restrict__ Vto) {
    __shared__ short As[128 * 64];
    __shared__ short Bs[128 * 64];
    const int tid = threadIdx.x;
    const int lane = tid & 63, wave = tid >> 6;
    const int l15 = lane & 15, quad = lane >> 4;

    // XCD swizzle: 8 XCDs x 8 m x 18 n = 1152 blocks
    const int flat = blockIdx.x;
    const int xcd = flat & 7;
    const int local = flat >> 3;
    const int mloc = local & 7, nloc = local >> 3;
    const int m0 = (xcd * 8 + mloc) * 128;
    const int n0 = nloc * 128;

    const int wm = (wave >> 1) * 64, wn = (wave & 1) * 64;
    const int r8 = wave * 8 + (lane >> 3);
    const int c8 = lane & 7;
    const int sc = ((c8 ^ (r8 & 7)) << 3);   // swizzled source chunk (elems)

    const int sn = n0 + wn;                  // wave-uniform output chunk
    const int which = sn / 768;
    const bool swapAB = (which != 2);        // Q/K waves compute C^T

    floatx4 acc[4][4] = {};
    for (int k0 = 0; k0 < DIM; k0 += 64) {
#pragma unroll
        for (int i = 0; i < 4; ++i) {
            int row = i * 32 + r8;
            glds16(&A[(size_t)(m0 + row) * DIM + k0 + sc], &As[(size_t)(i * 32 + wave * 8) * 64]);
            glds16(&Bt[(size_t)(n0 + row) * DIM + k0 + sc], &Bs[(size_t)(i * 32 + wave * 8) * 64]);
        }
        __syncthreads();
#pragma unroll
        for (int ks = 0; ks < 2; ++ks) {
            short8 a[4], b[4];
#pragma unroll
            for (int mt = 0; mt < 4; ++mt)
                a[mt] = *(const short8*)&As[swz8(wm + mt * 16 + l15, ks * 32 + quad * 8)];
#pragma unroll
            for (int nt = 0; nt < 4; ++nt)
                b[nt] = *(const short8*)&Bs[swz8(wn + nt * 16 + l15, ks * 32 + quad * 8)];
            if (swapAB) {
#pragma unroll
                for (int mt = 0; mt < 4; ++mt)
#pragma unroll
                    for (int nt = 0; nt < 4; ++nt)
                        acc[mt][nt] = mfma16(b[nt], a[mt], acc[mt][nt]);
            } else {
#pragma unroll
                for (int mt = 0; mt < 4; ++mt)
#pragma unroll
                    for (int nt = 0; nt < 4; ++nt)
                        acc[mt][nt] = mfma16(a[mt], b[nt], acc[mt][nt]);
            }
        }
        __syncthreads();
    }

    // ---- epilogue: direct stores into fragment-linear tiles ----
    const int h = (sn - which * 768) >> 6;
    const int bb = (m0 + wm) >> 11;

    if (which != 2) {
        // swapped acc: lane covers t = wm + mt*16 + l15, d = nt*16 + quad*4 .. +3
        const bool isQ = (which == 0);
        short* dst = isQ ? Qo : Ko;
        const size_t tb = isQ
            ? ((size_t)(bb * HEADS + h) * 16 + ((m0 & 2047) >> 7)) * 8192
            : ((size_t)(bb * HEADS + h) * 32 + (((m0 + wm) & 2047) >> 6)) * 4096;
#pragma unroll
        for (int mt = 0; mt < 4; ++mt)
#pragma unroll
            for (int nt = 0; nt < 4; ++nt) {
                int cl = (mt & 1) * 16 + l15 + 32 * (quad >> 1);
                int off = isQ
                    ? (((wm >> 5) + (mt >> 1)) * 2048 + nt * 512 + cl * 8 + (quad & 1) * 4)
                    : (((mt >> 1) * 4 + nt) * 512 + cl * 8 + (quad & 1) * 4);
                uint2 pk;
                pk.x = pack2(acc[mt][nt][0], acc[mt][nt][1]);
                pk.y = pack2(acc[mt][nt][2], acc[mt][nt][3]);
                *(uint2*)&dst[tb + off] = pk;
            }
    } else {
        // V (unswapped): lane covers d = nt*16 + l15, kv = wm-rel mt*16 + quad*4 + r
        const size_t tb = ((size_t)(bb * HEADS + h) * 32 + (((m0 + wm) & 2047) >> 6)) * 4096;
#pragma unroll
        for (int mt = 0; mt < 4; ++mt)
#pragma unroll
            for (int nt = 0; nt < 4; ++nt) {
                int cl = (nt & 1) * 16 + l15 + 32 * (quad >> 1);
                int off = ((nt >> 1) * 4 + mt) * 512 + cl * 8 + (quad & 1) * 4;
                uint2 pk;
                pk.x = pack2(acc[mt][nt][0], acc[mt][nt][1]);  // consecutive kv
                pk.y = pack2(acc[mt][nt][2], acc[mt][nt][3]);
                *(uint2*)&Vto[tb + off] = pk;
            }
    }
}

// ---------------------------------------------------------------------------
// MFMA flash attention, 32x32x16, fragment-linear tiles, FULLY INTERLEAVED:
//   4 waves x 32 q-rows over the full 64-kv tile.
//   - QK(t) and PV(t-1) MFMAs interleave INSTRUCTION-BY-INSTRUCTION
//     (sa0,o0,sa1,o1 round-robin): 4 independent accumulator chains with
//     4-instr spacing >= MFMA latency -> no dependency stalls (R5's
//     cluster-sequential version still stalled on 2-chain 4-deep groups).
//   - pf(t-1) carried in regs; SOFTPACK overwrites pfp in place (PV's reads
//     precede in program order) -- no copy.
//   - 3-deep K/V LDS buffers, 1 barrier/iter, depth-1 prefetch (WAR-safe).
//   - all ds_reads are base + lane*16 + constant (conflict-free, no addr math)
// ---------------------------------------------------------------------------
__global__ __launch_bounds__(256, 3) void attn_mfma(const short* __restrict__ Q,
                                                    const short* __restrict__ K,
                                                    const short* __restrict__ Vt,
                                                    short* __restrict__ O) {
    // 3 buffers x (K 4096 | V 4096) shorts = 48 KB
    __shared__ __align__(16) short smem[24576];
    const int tid = threadIdx.x;
    const int lane = tid & 63, wave = tid >> 6;    // 4 waves
    const int l31 = lane & 31, hi = lane >> 5;
    const int flat = blockIdx.x;
    const int xcd = flat & 7, li = flat >> 3;      // li 0..95
    const int bh = xcd + (li % 6) * 8;             // bh % 8 == xcd (K/V L2-local)
    const int q0 = (li / 6) * 128;
    const size_t base = (size_t)bh * SEQ * DHEAD;  // shorts
    const int lane8 = lane * 8;

    // ---- stage Q tile (16 KB fragment-linear) into smem[0..8192) ----
    {
        size_t qtb = base + (size_t)(q0 >> 7) * 8192;
#pragma unroll
        for (int c = 0; c < 4; ++c) {
            int s = wave * 4 + c;
            glds16(&Q[qtb + s * 512 + lane8], &smem[s * 512]);
        }
    }
    __syncthreads();
    short8 qf[4];   // B-frags: q-col = l31 (wave's group), k = d = ks*16+hi*8+e
#pragma unroll
    for (int ks = 0; ks < 4; ++ks)
        qf[ks] = *(const short8*)&smem[wave * 2048 + ks * 512 + lane8];
    __syncthreads();   // Q in regs; smem free for K/V buffers

    floatx16 o0 = {}, o1 = {};   // O^T rows d = (reg&3)+8*(reg>>2)+4*hi (+32 for o1), col q = l31
    float lsum = 0.f;

    const int seg0 = (2 * wave + 0) * 512;   // this wave's staging segments
    const int seg1 = (2 * wave + 1) * 512;

#define STAGE(tt, buf) {                                                \
        size_t ktb_ = base + (size_t)(tt) * 4096;                       \
        glds16(&K[ktb_ + seg0 + lane8], &(buf)[seg0]);                  \
        glds16(&K[ktb_ + seg1 + lane8], &(buf)[seg1]);                  \
        glds16(&Vt[ktb_ + seg0 + lane8], &(buf)[4096 + seg0]);          \
        glds16(&Vt[ktb_ + seg1 + lane8], &(buf)[4096 + seg1]);          \
    }

    // p = exp2(s); pack + permlane32_swap -> PV B-frags (in-register).
    // D reg r (=rr+4*blk) holds kv = rr + 8*blk + 4*hi (within its 32-kv tile);
    // B-frag dword j needs kv = hi*8 + 2j per 16-kv chunk: P32-swap blk pairs.
#define SOFTPACK(SA, PFA, PFB) {                                              \
        float e0_  = __builtin_amdgcn_exp2f(SA[0]);                           \
        float e1_  = __builtin_amdgcn_exp2f(SA[1]);                           \
        float e2_  = __builtin_amdgcn_exp2f(SA[2]);                           \
        float e3_  = __builtin_amdgcn_exp2f(SA[3]);                           \
        float e4_  = __builtin_amdgcn_exp2f(SA[4]);                           \
        float e5_  = __builtin_amdgcn_exp2f(SA[5]);                           \
        float e6_  = __builtin_amdgcn_exp2f(SA[6]);                           \
        float e7_  = __builtin_amdgcn_exp2f(SA[7]);                           \
        float e8_  = __builtin_amdgcn_exp2f(SA[8]);                           \
        float e9_  = __builtin_amdgcn_exp2f(SA[9]);                           \
        float e10_ = __builtin_amdgcn_exp2f(SA[10]);                          \
        float e11_ = __builtin_amdgcn_exp2f(SA[11]);                          \
        float e12_ = __builtin_amdgcn_exp2f(SA[12]);                          \
        float e13_ = __builtin_amdgcn_exp2f(SA[13]);                          \
        float e14_ = __builtin_amdgcn_exp2f(SA[14]);                          \
        float e15_ = __builtin_amdgcn_exp2f(SA[15]);                          \
        lsum += (((e0_ + e1_) + (e2_ + e3_)) + ((e4_ + e5_) + (e6_ + e7_)))   \
              + (((e8_ + e9_) + (e10_ + e11_)) + ((e12_ + e13_) + (e14_ + e15_))); \
        unsigned A0_ = cvtpk(e0_, e1_),   A1_ = cvtpk(e2_, e3_);              \
        unsigned B0_ = cvtpk(e4_, e5_),   B1_ = cvtpk(e6_, e7_);              \
        unsigned C0_ = cvtpk(e8_, e9_),   C1_ = cvtpk(e10_, e11_);            \
        unsigned E0_ = cvtpk(e12_, e13_), E1_ = cvtpk(e14_, e15_);            \
        asm("v_permlane32_swap_b32 %0, %1" : "+v"(A0_), "+v"(B0_));           \
        asm("v_permlane32_swap_b32 %0, %1" : "+v"(A1_), "+v"(B1_));           \
        asm("v_permlane32_swap_b32 %0, %1" : "+v"(C0_), "+v"(E0_));           \
        asm("v_permlane32_swap_b32 %0, %1" : "+v"(C1_), "+v"(E1_));           \
        uintx4 wa_ = {A0_, A1_, B0_, B1_};                                    \
        uintx4 wb_ = {C0_, C1_, E0_, E1_};                                    \
        PFA = __builtin_bit_cast(short8, wa_);                                \
        PFB = __builtin_bit_cast(short8, wb_);                                \
    }

    short8 pfp[4];   // pf(t-1) carry

    // prologue: stage tile 0 -> buf0
    STAGE(0, smem);
    // ---- t = 0 peel: QK + softmax only (no PV yet) ----
    {
        __syncthreads();               // tile 0 resident
        STAGE(1, smem + 8192);         // prefetch tile 1 -> buf1
        floatx16 sa0 = {}, sa1 = {};
        __builtin_amdgcn_s_setprio(1);
#pragma unroll
        for (int c = 0; c < 4; ++c) {
            short8 kf0 = *(const short8*)&smem[c * 512 + lane8];
            short8 kf1 = *(const short8*)&smem[(4 + c) * 512 + lane8];
            sa0 = mfma32(kf0, qf[c], sa0);
            sa1 = mfma32(kf1, qf[c], sa1);
        }
        __builtin_amdgcn_s_setprio(0);
        SOFTPACK(sa0, pfp[0], pfp[1])
        SOFTPACK(sa1, pfp[2], pfp[3])
    }

    int bp = 0, bc = 1, bn = 2;
    for (int t = 1; t < 32; ++t) {
        __syncthreads();               // tile t resident; buf[bn] free
        const short* curb = smem + bc * 8192;        // K(t)
        const short* prvv = smem + bp * 8192 + 4096; // V(t-1)
        if (t < 31)
            STAGE(t + 1, smem + bn * 8192);

        // ---- fused QK(t) + PV(t-1): 4 chains round-robin, no MFMA stalls ----
        floatx16 sa0 = {}, sa1 = {};
        __builtin_amdgcn_s_setprio(1);
#pragma unroll
        for (int c = 0; c < 4; ++c) {
            short8 kf0 = *(const short8*)&curb[c * 512 + lane8];
            short8 kf1 = *(const short8*)&curb[(4 + c) * 512 + lane8];
            short8 vf0 = *(const short8*)&prvv[c * 512 + lane8];
            short8 vf1 = *(const short8*)&prvv[(4 + c) * 512 + lane8];
            sa0 = mfma32(kf0, qf[c], sa0);
            o0  = mfma32(vf0, pfp[c], o0);
            sa1 = mfma32(kf1, qf[c], sa1);
            o1  = mfma32(vf1, pfp[c], o1);
        }
        __builtin_amdgcn_s_setprio(0);

        // sm(t) overwrites pfp in place (PV(t-1) reads precede in prog order)
        SOFTPACK(sa0, pfp[0], pfp[1])
        SOFTPACK(sa1, pfp[2], pfp[3])

        // rotate buffers
        bp = bc; bc = bn; bn = (bn == 2) ? 0 : bn + 1;
    }
    // final PV for tile 31 (its buffer is bp after the last rotate)
    {
        const short* prvv = smem + bp * 8192 + 4096;
        __builtin_amdgcn_s_setprio(1);
#pragma unroll
        for (int c = 0; c < 4; ++c) {
            short8 vf0 = *(const short8*)&prvv[c * 512 + lane8];
            short8 vf1 = *(const short8*)&prvv[(4 + c) * 512 + lane8];
            o0 = mfma32(vf0, pfp[c], o0);
            o1 = mfma32(vf1, pfp[c], o1);
        }
        __builtin_amdgcn_s_setprio(0);
    }

#undef SOFTPACK
#undef STAGE

    // ---- epilogue: lane pair (hi^1) holds the other 32 kv -> one xor-32 ----
    float s = lsum + __shfl_xor(lsum, 32);
    float inv = 1.f / s;

    const int b = bh / HEADS, h = bh - b * HEADS;
    const int tq = q0 + wave * 32 + l31;
    size_t rowo = ((size_t)(b * SEQ + tq)) * DIM + h * DHEAD;
#pragma unroll
    for (int blk = 0; blk < 4; ++blk) {
        int d0 = 8 * blk + 4 * hi;
        uint2 p0, p1;
        p0.x = cvtpk(o0[4 * blk + 0] * inv, o0[4 * blk + 1] * inv);
        p0.y = cvtpk(o0[4 * blk + 2] * inv, o0[4 * blk + 3] * inv);
        *(uint2*)&O[rowo + d0] = p0;
        p1.x = cvtpk(o1[4 * blk + 0] * inv, o1[4 * blk + 1] * inv);
        p1.y = cvtpk(o1[4 * blk + 2] * inv, o1[4 * blk + 3] * inv);
        *(uint2*)&O[rowo + 32 + d0] = p1;
    }
}

// ---------------------------------------------------------------------------
// out = attnB @ Wout (via Wot [768][768]), fp32 output; glds-staged.
// 64x128 tile: grid 768 = 3.0 blocks/CU even. C^T swap -> dwordx4 stores.
// ---------------------------------------------------------------------------
__global__ __launch_bounds__(256) void gemm_out(const short* __restrict__ A,
                                                const short* __restrict__ Bt,
                                                float* __restrict__ out) {
    __shared__ short As[64 * 64];
    __shared__ short Bs[128 * 64];
    const int tid = threadIdx.x;
    const int lane = tid & 63, wave = tid >> 6;
    const int l15 = lane & 15, quad = lane >> 4;
    const int m0 = blockIdx.y * 64, n0 = blockIdx.x * 128;
    const int wn = wave * 32;                 // wave's 32-col slice; rows shared
    const int r8 = wave * 8 + (lane >> 3);
    const int sc = (((lane & 7) ^ (r8 & 7)) << 3);

    floatx4 acc[4][2] = {};
    for (int k0 = 0; k0 < DIM; k0 += 64) {
#pragma unroll
        for (int i = 0; i < 2; ++i) {
            int row = i * 32 + r8;
            glds16(&A[(size_t)(m0 + row) * DIM + k0 + sc], &As[(size_t)(i * 32 + wave * 8) * 64]);
        }
#pragma unroll
        for (int i = 0; i < 4; ++i) {
            int row = i * 32 + r8;
            glds16(&Bt[(size_t)(n0 + row) * DIM + k0 + sc], &Bs[(size_t)(i * 32 + wave * 8) * 64]);
        }
        __syncthreads();
#pragma unroll
        for (int ks = 0; ks < 2; ++ks) {
            short8 a[4], b[2];
#pragma unroll
            for (int mt = 0; mt < 4; ++mt)
                a[mt] = *(const short8*)&As[swz8(mt * 16 + l15, ks * 32 + quad * 8)];
#pragma unroll
            for (int nt = 0; nt < 2; ++nt)
                b[nt] = *(const short8*)&Bs[swz8(wn + nt * 16 + l15, ks * 32 + quad * 8)];
#pragma unroll
            for (int mt = 0; mt < 4; ++mt)
#pragma unroll
                for (int nt = 0; nt < 2; ++nt)
                    acc[mt][nt] = mfma16(b[nt], a[mt], acc[mt][nt]);  // C^T
        }
        __syncthreads();
    }

    // swapped: m = mt*16+l15, n = wn+nt*16+quad*4..+3 -> dwordx4 stores
#pragma unroll
    for (int mt = 0; mt < 4; ++mt)
#pragma unroll
        for (int nt = 0; nt < 2; ++nt) {
            int m = m0 + mt * 16 + l15;
            int n = n0 + wn + nt * 16 + quad * 4;
            *(floatx4*)&out[(size_t)m * DIM + n] = acc[mt][nt];
        }
}

// ---------------------------------------------------------------------------
extern "C" void kernel_launch(void* const* d_in, const int* in_sizes, int n_in,
                              void* d_out, int out_size, void* d_ws, size_t ws_size,
                              hipStream_t stream) {
    const float* x    = (const float*)d_in[0];  // [4,2048,768] fp32
    const float* Wqkv = (const float*)d_in[1];  // [768,2304]  fp32
    const float* Wout = (const float*)d_in[2];  // [768,768]   fp32
    float* out = (float*)d_out;                 // [4,2048,768] fp32

    const size_t NE = (size_t)NROW * DIM;       // 6291456
    short* xb  = (short*)d_ws;                  // x bf16; later reused as attnB
    short* Wqt = xb + NE;                       // [2304][768] (col-permuted, Q-rows pre-scaled)
    short* Wot = Wqt + (size_t)QKVN * DIM;      // [768][768]
    short* Qw  = Wot + (size_t)DIM * DIM;       // fragment-linear 128q tiles
    short* Kw  = Qw + NE;                       // fragment-linear 64kv tiles
    short* Vtw = Kw + NE;                       // fragment-linear V^T tiles

    prep<<<6144 + 1728 + 576, 256, 0, stream>>>(x, xb, Wqkv, Wqt, Wout, Wot);
    gemm_qkv<<<8 * 8 * 18, 256, 0, stream>>>(xb, Wqt, Qw, Kw, Vtw);
    // xb (x in bf16) is dead after gemm_qkv -> reuse as attention output buffer
    attn_mfma<<<768, 256, 0, stream>>>(Qw, Kw, Vtw, xb);
    gemm_out<<<dim3(DIM / 128, NROW / 64), 256, 0, stream>>>(xb, Wot, out);
}